// Round 22
// baseline (736.715 us; speedup 1.0000x reference)
//
#include <hip/hip_runtime.h>
#include <hip/hip_bf16.h>
#include <math.h>

#define DM 256
#define NHEAD 8
#define HD 32
#define NL 4
#define BATCH 8
#define SEQ 4096
#define KCLS 10
#define M_TOK (BATCH*SEQ)   // 32768

#define BKG 64

#define PADPOS 5120          // padded sorted positions per batch (each cluster 64-aligned)
#define NWIN (PADPOS/64)     // 80 msg windows per batch
#define KVWIN 20             // kv windows per batch (256 positions each)
#define NGRP (KVWIN*4)       // 80 groups of 64 per batch-head

using bf16x8 = __attribute__((ext_vector_type(8))) short;
using f32x4  = __attribute__((ext_vector_type(4))) float;

__device__ __forceinline__ unsigned short f2bf(float f) {
    __hip_bfloat16 b = __float2bfloat16(f);
    return __builtin_bit_cast(unsigned short, b);
}
__device__ __forceinline__ float bf2f(unsigned short u) {
    unsigned v = (unsigned)u << 16;
    return __builtin_bit_cast(float, v);
}

__device__ __forceinline__ float wave_reduce_sum(float v) {
    #pragma unroll
    for (int off = 32; off > 0; off >>= 1) v += __shfl_xor(v, off, 64);
    return v;
}

// ---------------- fc norms ----------------
__global__ __launch_bounds__(64) void fcn_kernel(const float* __restrict__ fc,
                                                 float* __restrict__ fcn) {
    int bk = blockIdx.x;
    int lane = threadIdx.x;
    float4 fv = *(const float4*)(fc + (size_t)bk * DM + lane * 4);
    float n = fv.x*fv.x + fv.y*fv.y + fv.z*fv.z + fv.w*fv.w;
    n = wave_reduce_sum(n);
    if (lane == 0) fcn[bk] = sqrtf(n);
}

// ---------------- fused init + routing (64 lanes/token, fully coalesced) ----------------
__global__ void route_kernel(const float* __restrict__ feat, const float* __restrict__ fc,
                             const float* __restrict__ fcn,
                             float* __restrict__ x, unsigned short* __restrict__ xm,
                             int* __restrict__ seg) {
    int wid = (int)((blockIdx.x * (size_t)blockDim.x + threadIdx.x) >> 6);
    int lane = threadIdx.x & 63;
    if (wid >= M_TOK) return;
    int b = wid / SEQ;
    float4 xv = *(const float4*)(feat + (size_t)wid * DM + lane * 4);
    *(float4*)(x + (size_t)wid * DM + lane * 4) = xv;
    ushort4 u; u.x = f2bf(xv.x); u.y = f2bf(xv.y); u.z = f2bf(xv.z); u.w = f2bf(xv.w);
    *(ushort4*)(xm + (size_t)wid * 512 + lane * 4) = u;
    float nb2 = xv.x*xv.x + xv.y*xv.y + xv.z*xv.z + xv.w*xv.w;
    nb2 = wave_reduce_sum(nb2);
    float nb = sqrtf(nb2);
    float best = -1e30f; int bestk = 0;
    for (int k = 0; k < KCLS; ++k) {
        float4 fv = *(const float4*)(fc + ((size_t)(b * KCLS + k)) * DM + lane * 4);
        float d = fv.x*xv.x + fv.y*xv.y + fv.z*xv.z + fv.w*xv.w;
        d = wave_reduce_sum(d);
        float sim = d / fmaxf(fcn[b * KCLS + k] * nb, 1e-8f);
        if (sim > best) { best = sim; bestk = k; }
    }
    if (lane == 0) seg[wid] = bestk;
}

// ---------------- deterministic cluster counting-sort ----------------
__global__ __launch_bounds__(256) void seg_count(const int* __restrict__ seg,
                                                 int* __restrict__ cnt) {
    __shared__ int wc[4][KCLS];
    int b = blockIdx.x >> 4, chunk = blockIdx.x & 15;
    int t = threadIdx.x, w = t >> 6, lane = t & 63;
    int c = seg[b * SEQ + chunk * 256 + t];
    #pragma unroll
    for (int cc = 0; cc < KCLS; ++cc) {
        unsigned long long m = __ballot(c == cc);
        if (lane == 0) wc[w][cc] = __popcll(m);
    }
    __syncthreads();
    if (t < KCLS)
        cnt[(b * 16 + chunk) * KCLS + t] = wc[0][t] + wc[1][t] + wc[2][t] + wc[3][t];
}

__global__ __launch_bounds__(256) void seg_scan(const int* __restrict__ cnt,
                                                int* __restrict__ chunkbase,
                                                int* __restrict__ wseg,
                                                int* __restrict__ psegp,
                                                int* __restrict__ grange,
                                                int* __restrict__ prange,
                                                int* __restrict__ pidxp) {
    __shared__ int sTot[BATCH][KCLS];
    __shared__ int sBase[BATCH][KCLS];
    int tid = threadIdx.x;
    if (tid < BATCH * KCLS) {
        int b = tid / KCLS, c = tid % KCLS;
        int run = 0;
        #pragma unroll
        for (int j = 0; j < 16; ++j) run += cnt[(b * 16 + j) * KCLS + c];
        sTot[b][c] = run;
    }
    __syncthreads();
    if (tid < BATCH) {
        int b = tid, pb = 0;
        for (int c = 0; c < KCLS; ++c) {
            sBase[b][c] = pb;
            int psz = (sTot[b][c] + 63) & ~63;
            grange[(b * KCLS + c) * 2]     = pb >> 6;
            grange[(b * KCLS + c) * 2 + 1] = (pb + psz) >> 6;
            prange[(b * KCLS + c) * 2]     = pb + sTot[b][c];   // pad start
            prange[(b * KCLS + c) * 2 + 1] = pb + psz;          // pad end
            int w0 = pb >> 6, w1 = (pb + psz) >> 6;
            for (int w = w0; w < w1; ++w) wseg[b * NWIN + w] = c;
            pb += psz;
        }
        for (int w = pb >> 6; w < NWIN; ++w) wseg[b * NWIN + w] = -1;
    }
    __syncthreads();
    for (int i = tid; i < BATCH * PADPOS; i += 256) {
        int b = i / PADPOS, pos = i % PADPOS;
        int c = KCLS - 1;
        #pragma unroll
        for (int cc = KCLS - 1; cc >= 1; --cc)
            if (pos < sBase[b][cc]) c = cc - 1;
        psegp[i] = c;
        pidxp[i] = -1;                       // pad marker; scatter overwrites real slots
    }
    if (tid < BATCH * KCLS) {
        int b = tid / KCLS, c = tid % KCLS;
        int pre = 0;
        #pragma unroll
        for (int j = 0; j < 16; ++j) {
            chunkbase[(b * 16 + j) * KCLS + c] = sBase[b][c] + pre;
            pre += cnt[(b * 16 + j) * KCLS + c];
        }
    }
}

// scatter: pidxp[b][pos] = token; sortposG[b*SEQ+l] = b*PADPOS+pos
__global__ __launch_bounds__(256) void seg_scatter(const int* __restrict__ seg,
                                                   const int* __restrict__ chunkbase,
                                                   int* __restrict__ pidxp,
                                                   int* __restrict__ sortposG) {
    __shared__ int wc[4][KCLS];
    int b = blockIdx.x >> 4, chunk = blockIdx.x & 15;
    int t = threadIdx.x, w = t >> 6, lane = t & 63;
    int l = chunk * 256 + t;
    int c = seg[b * SEQ + l];
    int rank_w = 0;
    #pragma unroll
    for (int cc = 0; cc < KCLS; ++cc) {
        unsigned long long m = __ballot(c == cc);
        if (lane == 0) wc[w][cc] = __popcll(m);
        if (cc == c) rank_w = __popcll(m & ((1ULL << lane) - 1ULL));
    }
    __syncthreads();
    int rank = rank_w;
    for (int wp = 0; wp < 4; ++wp)
        if (wp < w) rank += wc[wp][c];
    int pos = chunkbase[(b * 16 + chunk) * KCLS + c] + rank;
    pidxp[b * PADPOS + pos] = l;
    sortposG[b * SEQ + l] = b * PADPOS + pos;
}

// ---------------- zero pad rows of sorted K/V (prange-driven, 80 blocks) ----------------
__global__ __launch_bounds__(256) void zero_pads(const int* __restrict__ prange,
                                                 unsigned short* __restrict__ Kb,
                                                 unsigned short* __restrict__ Vb) {
    int bc = blockIdx.x;               // b*KCLS + c
    int b = bc / KCLS;
    int ps = prange[bc * 2], pe = prange[bc * 2 + 1];
    int nrows = pe - ps;
    int t = threadIdx.x;
    bf16x8 z = (bf16x8){0,0,0,0,0,0,0,0};
    for (int idx = t; idx < nrows * 32; idx += 256) {
        int r = idx >> 5, c8 = (idx & 31) * 8;
        size_t row = (size_t)b * PADPOS + ps + r;
        *(bf16x8*)(Kb + row * DM + c8) = z;
        *(bf16x8*)(Vb + row * DM + c8) = z;
    }
}

// ---------------- fused weight transpose+convert: ALL layers in ONE dispatch ----------------
__global__ __launch_bounds__(256) void transpose_all(
    const float* __restrict__ Wq, const float* __restrict__ Wk,
    const float* __restrict__ Wv, const float* __restrict__ Wm,
    const float* __restrict__ W1, const float* __restrict__ W2,
    unsigned short* __restrict__ WqkvT, unsigned short* __restrict__ WmT,
    unsigned short* __restrict__ W1T, unsigned short* __restrict__ W2T)
{
    __shared__ float s[64][65];
    int bid = blockIdx.x;
    int li = bid / 160, r = bid % 160;
    const float* src; unsigned short* dst; int K, N, kx, ny;
    if (r < 64) {
        int which = r >> 4, idx = r & 15;
        K = 256; N = 256; kx = idx & 3; ny = idx >> 2;
        if (which == 0)      { src = Wq + (size_t)li*65536; dst = WqkvT + (size_t)li*768*256; }
        else if (which == 1) { src = Wk + (size_t)li*65536; dst = WqkvT + (size_t)li*768*256 + 65536; }
        else if (which == 2) { src = Wv + (size_t)li*65536; dst = WqkvT + (size_t)li*768*256 + 131072; }
        else                 { src = Wm + (size_t)li*65536; dst = WmT + (size_t)li*65536; }
    } else if (r < 128) {
        int idx = r - 64;
        K = 512; N = 512; kx = idx & 7; ny = idx >> 3;
        src = W1 + (size_t)li*262144; dst = W1T + (size_t)li*262144;
    } else {
        int idx = r - 128;
        K = 512; N = 256; kx = idx & 7; ny = idx >> 3;
        src = W2 + (size_t)li*131072; dst = W2T + (size_t)li*131072;
    }
    int k0 = kx * 64, n0 = ny * 64;
    int t = threadIdx.x;
    int rr = t >> 4, c4 = (t & 15) * 4;
    #pragma unroll
    for (int i = 0; i < 4; ++i) {
        float4 v = *(const float4*)(src + (size_t)(k0 + rr + i*16) * N + n0 + c4);
        s[c4+0][rr+i*16] = v.x; s[c4+1][rr+i*16] = v.y;
        s[c4+2][rr+i*16] = v.z; s[c4+3][rr+i*16] = v.w;
    }
    __syncthreads();
    #pragma unroll
    for (int i = 0; i < 4; ++i) {
        int nr = rr + i*16;
        ushort4 u;
        u.x = f2bf(s[nr][c4+0]); u.y = f2bf(s[nr][c4+1]);
        u.z = f2bf(s[nr][c4+2]); u.w = f2bf(s[nr][c4+3]);
        *(ushort4*)(dst + (size_t)(n0 + nr) * K + k0 + c4) = u;
    }
}

// ---------------- bf16 MFMA GEMM (128x256, 8 waves) + T2 swizzle + 2-phase dbuf pipeline ----------------
// T3/T4 minimum 2-phase (catalog recipe): STAGE(next) issued BEFORE compute(cur);
// drain vmcnt(0) AFTER MFMA (overlapped); ONE raw s_barrier per K-step.
template<int KD, int AS, int MODE>
__global__ __launch_bounds__(512, 4) void mfma_gemm(
    const unsigned short* __restrict__ A, const unsigned short* __restrict__ Bt,
    const int* __restrict__ sortpos,
    unsigned short* __restrict__ Ob0, unsigned short* __restrict__ Ob1,
    unsigned short* __restrict__ Ob2)
{
    __shared__ unsigned short As[2][128 * BKG];   // 2 x 16 KB
    __shared__ unsigned short Bs[2][256 * BKG];   // 2 x 32 KB
    __shared__ int sPos[128];
    int t = threadIdx.x;
    int lane = t & 63;
    int w = t >> 6;
    int wm = w & 1, wn = w >> 1;
    int li = lane & 15, lg = lane >> 4;
    int bm = blockIdx.x * 128;
    int bn = blockIdx.y * 256;

    if (MODE == 1 && t < 128) sPos[t] = sortpos[bm + t];

    f32x4 acc[4][4];
    #pragma unroll
    for (int m = 0; m < 4; ++m)
        #pragma unroll
        for (int n = 0; n < 4; ++n)
            acc[m][n] = (f32x4){0.f, 0.f, 0.f, 0.f};

    auto STAGE = [&](int buf, int k0) {
        #pragma unroll
        for (int i = 0; i < 2; ++i) {
            int chunk = i * 512 + t;
            int row = chunk >> 3, cc = chunk & 7;
            int scc = cc ^ (row & 7);
            __builtin_amdgcn_global_load_lds(
                (const __attribute__((address_space(1))) void*)(A + (size_t)(bm + row) * AS + k0 + scc * 8),
                (__attribute__((address_space(3))) void*)((char*)&As[buf][0] + chunk * 16), 16, 0, 0);
        }
        #pragma unroll
        for (int i = 0; i < 4; ++i) {
            int chunk = i * 512 + t;
            int row = chunk >> 3, cc = chunk & 7;
            int scc = cc ^ (row & 7);
            __builtin_amdgcn_global_load_lds(
                (const __attribute__((address_space(1))) void*)(Bt + (size_t)(bn + row) * KD + k0 + scc * 8),
                (__attribute__((address_space(3))) void*)((char*)&Bs[buf][0] + chunk * 16), 16, 0, 0);
        }
    };

    constexpr int NSTEP = KD / BKG;
    STAGE(0, 0);
    asm volatile("s_waitcnt vmcnt(0)" ::: "memory");
    __builtin_amdgcn_s_barrier();
    int cur = 0;
    #pragma unroll
    for (int step = 0; step < NSTEP; ++step) {
        if (step + 1 < NSTEP) STAGE(cur ^ 1, (step + 1) * BKG);   // loads in flight during MFMA
        const char* Ab = (const char*)&As[cur][0];
        const char* Bb = (const char*)&Bs[cur][0];
        #pragma unroll
        for (int kk = 0; kk < 2; ++kk) {
            int jc = kk * 4 + lg;
            bf16x8 af[4], bfr[4];
            #pragma unroll
            for (int m = 0; m < 4; ++m) {
                int R = wm*64 + m*16 + li;
                af[m] = *(const bf16x8*)(Ab + R * 128 + ((jc ^ (R & 7)) << 4));
            }
            #pragma unroll
            for (int n = 0; n < 4; ++n) {
                int R = wn*64 + n*16 + li;
                bfr[n] = *(const bf16x8*)(Bb + R * 128 + ((jc ^ (R & 7)) << 4));
            }
            #pragma unroll
            for (int m = 0; m < 4; ++m)
                #pragma unroll
                for (int n = 0; n < 4; ++n)
                    acc[m][n] = __builtin_amdgcn_mfma_f32_16x16x32_bf16(af[m], bfr[n], acc[m][n], 0, 0, 0);
        }
        // drain next-tile loads (overlapped with MFMA above) + retire our ds_reads
        asm volatile("s_waitcnt vmcnt(0) lgkmcnt(0)" ::: "memory");
        __builtin_amdgcn_sched_barrier(0);
        __builtin_amdgcn_s_barrier();
        cur ^= 1;
    }

    int lrow0 = wm * 64 + (lane >> 4) * 4;
    int lcol = wn * 64 + (lane & 15);
    if (MODE == 1) {
        unsigned short* Obuf = (bn < 256) ? Ob0 : (bn < 512) ? Ob1 : Ob2;
        const bool act = (bn < 512);
        #pragma unroll
        for (int m = 0; m < 4; ++m)
            #pragma unroll
            for (int n = 0; n < 4; ++n)
                #pragma unroll
                for (int j = 0; j < 4; ++j) {
                    float v = acc[m][n][j];
                    if (act) v = (v > 0.f) ? v + 1.f : expf(v);
                    int drow = sPos[lrow0 + m*16 + j];
                    Obuf[(size_t)drow * 256 + lcol + n*16] = f2bf(v);
                }
    } else {
        #pragma unroll
        for (int m = 0; m < 4; ++m)
            #pragma unroll
            for (int n = 0; n < 4; ++n)
                #pragma unroll
                for (int j = 0; j < 4; ++j)
                    Ob0[(size_t)(bm + lrow0 + m*16 + j) * 512 + bn + lcol + n*16] =
                        f2bf(fmaxf(acc[m][n][j], 0.f));
    }
}

// ---------------- fused GEMM + LayerNorm (BM=64, BN=256, 256 thr) + T2 swizzle ----------------
template<int KD, int LNMODE>
__global__ __launch_bounds__(256) void gemm_ln(
    const unsigned short* __restrict__ A, const unsigned short* __restrict__ Bt,
    const float* __restrict__ g, const float* __restrict__ bb,
    float* __restrict__ x, unsigned short* __restrict__ xm)
{
    __shared__ unsigned short As[64 * BKG];
    __shared__ unsigned short Bs[256 * BKG];
    __shared__ float redS[4][64];
    __shared__ float redQ[4][64];
    int t = threadIdx.x;
    int lane = t & 63;
    int w = t >> 6;
    int li = lane & 15, lg = lane >> 4;
    int bm = blockIdx.x * 64;

    f32x4 acc[4][4];
    #pragma unroll
    for (int m = 0; m < 4; ++m)
        #pragma unroll
        for (int n = 0; n < 4; ++n)
            acc[m][n] = (f32x4){0.f, 0.f, 0.f, 0.f};

    for (int k0 = 0; k0 < KD; k0 += BKG) {
        #pragma unroll
        for (int i = 0; i < 2; ++i) {
            int chunk = i * 256 + t;
            int row = chunk >> 3, cc = chunk & 7;
            int scc = cc ^ (row & 7);
            __builtin_amdgcn_global_load_lds(
                (const __attribute__((address_space(1))) void*)(A + (size_t)(bm + row) * KD + k0 + scc * 8),
                (__attribute__((address_space(3))) void*)((char*)As + chunk * 16), 16, 0, 0);
        }
        #pragma unroll
        for (int i = 0; i < 8; ++i) {
            int chunk = i * 256 + t;
            int row = chunk >> 3, cc = chunk & 7;
            int scc = cc ^ (row & 7);
            __builtin_amdgcn_global_load_lds(
                (const __attribute__((address_space(1))) void*)(Bt + (size_t)row * KD + k0 + scc * 8),
                (__attribute__((address_space(3))) void*)((char*)Bs + chunk * 16), 16, 0, 0);
        }
        asm volatile("s_waitcnt vmcnt(0)");
        __syncthreads();
        #pragma unroll
        for (int kk = 0; kk < 2; ++kk) {
            int jc = kk * 4 + lg;
            bf16x8 af[4], bfr[4];
            #pragma unroll
            for (int m = 0; m < 4; ++m) {
                int R = m*16 + li;
                af[m] = *(const bf16x8*)((const char*)As + R * 128 + ((jc ^ (R & 7)) << 4));
            }
            #pragma unroll
            for (int n = 0; n < 4; ++n) {
                int R = w*64 + n*16 + li;
                bfr[n] = *(const bf16x8*)((const char*)Bs + R * 128 + ((jc ^ (R & 7)) << 4));
            }
            #pragma unroll
            for (int m = 0; m < 4; ++m)
                #pragma unroll
                for (int n = 0; n < 4; ++n)
                    acc[m][n] = __builtin_amdgcn_mfma_f32_16x16x32_bf16(af[m], bfr[n], acc[m][n], 0, 0, 0);
        }
        __syncthreads();
    }

    float vs[4][4], vq[4][4];
    #pragma unroll
    for (int m = 0; m < 4; ++m)
        #pragma unroll
        for (int j = 0; j < 4; ++j) {
            float s = 0.f, q = 0.f;
            #pragma unroll
            for (int n = 0; n < 4; ++n) {
                float v = acc[m][n][j];
                s += v; q += v * v;
            }
            #pragma unroll
            for (int msk = 1; msk < 16; msk <<= 1) {
                s += __shfl_xor(s, msk, 64);
                q += __shfl_xor(q, msk, 64);
            }
            vs[m][j] = s; vq[m][j] = q;
        }
    if (li == 0) {
        #pragma unroll
        for (int m = 0; m < 4; ++m)
            #pragma unroll
            for (int j = 0; j < 4; ++j) {
                redS[w][m*16 + lg*4 + j] = vs[m][j];
                redQ[w][m*16 + lg*4 + j] = vq[m][j];
            }
    }
    __syncthreads();

    float gv[4], bv[4];
    #pragma unroll
    for (int n = 0; n < 4; ++n) {
        int col = w*64 + n*16 + li;
        gv[n] = g[col]; bv[n] = bb[col];
    }
    #pragma unroll
    for (int m = 0; m < 4; ++m)
        #pragma unroll
        for (int j = 0; j < 4; ++j) {
            int r = m*16 + lg*4 + j;
            float S = redS[0][r] + redS[1][r] + redS[2][r] + redS[3][r];
            float Q = redQ[0][r] + redQ[1][r] + redQ[2][r] + redQ[3][r];
            float mu = S * (1.f / 256.f);
            float var = Q * (1.f / 256.f) - mu * mu;
            float rs = rsqrtf(var + 1e-5f);
            #pragma unroll
            for (int n = 0; n < 4; ++n) {
                int col = w*64 + n*16 + li;
                float o = gv[n] * (acc[m][n][j] - mu) * rs + bv[n];
                if (LNMODE == 1) {
                    xm[(size_t)(bm + r) * 512 + 256 + col] = f2bf(o);
                } else {
                    size_t idx = (size_t)(bm + r) * 256 + col;
                    float xv = x[idx] + o;
                    x[idx] = xv;
                    xm[(size_t)(bm + r) * 512 + col] = f2bf(xv);
                }
            }
        }
}

// ---------------- KV / Ksum: fp32 LDS staging, per-64-group unconditional flush ----------------
__global__ __launch_bounds__(256) void kv_kernel(
    const unsigned short* __restrict__ Ksrt, const unsigned short* __restrict__ Vsrt,
    float* __restrict__ part)
{
    __shared__ float sK[64 * 33];
    __shared__ float sV[64 * 33];
    int blk = blockIdx.x;
    int s = blk % KVWIN;
    int bh = blk / KVWIN;
    int b = bh >> 3, h = bh & 7;
    int t = threadIdx.x;
    int d = t >> 3, e0 = (t & 7) * 4;
    int srow = t >> 2, soff = (t & 3) * 8;
    const size_t rowbase = (size_t)(b * PADPOS + s * 256);
    float* pball = part + ((size_t)bh * NGRP + s * 4) * 1056;

    for (int g = 0; g < 4; ++g) {
        size_t gsrc = (rowbase + g * 64 + srow) * DM + h * HD + soff;
        bf16x8 k8 = *(const bf16x8*)(Ksrt + gsrc);
        bf16x8 v8 = *(const bf16x8*)(Vsrt + gsrc);
        float4 ka, kb, va, vb;
        ka.x = bf2f((unsigned short)k8[0]); ka.y = bf2f((unsigned short)k8[1]);
        ka.z = bf2f((unsigned short)k8[2]); ka.w = bf2f((unsigned short)k8[3]);
        kb.x = bf2f((unsigned short)k8[4]); kb.y = bf2f((unsigned short)k8[5]);
        kb.z = bf2f((unsigned short)k8[6]); kb.w = bf2f((unsigned short)k8[7]);
        va.x = bf2f((unsigned short)v8[0]); va.y = bf2f((unsigned short)v8[1]);
        va.z = bf2f((unsigned short)v8[2]); va.w = bf2f((unsigned short)v8[3]);
        vb.x = bf2f((unsigned short)v8[4]); vb.y = bf2f((unsigned short)v8[5]);
        vb.z = bf2f((unsigned short)v8[6]); vb.w = bf2f((unsigned short)v8[7]);
        *(float4*)(sK + srow * 33 + soff)     = ka;
        *(float4*)(sK + srow * 33 + soff + 4) = kb;
        *(float4*)(sV + srow * 33 + soff)     = va;
        *(float4*)(sV + srow * 33 + soff + 4) = vb;
        __syncthreads();

        float4 a = {0.f, 0.f, 0.f, 0.f};
        float ks = 0.f;
        #pragma unroll 8
        for (int l = 0; l < 64; ++l) {
            float kd = sK[l * 33 + d];
            float4 v4 = *(const float4*)(sV + l * 33 + e0);
            a.x = fmaf(kd, v4.x, a.x);
            a.y = fmaf(kd, v4.y, a.y);
            a.z = fmaf(kd, v4.z, a.z);
            a.w = fmaf(kd, v4.w, a.w);
            ks += kd;
        }
        float* pb = pball + g * 1056;
        *(float4*)(pb + d * 32 + e0) = a;
        if ((t & 7) == 0) pb[1024 + d] = ks;
        __syncthreads();
    }
}

// ---------------- reduce group partials -> KV, Ks ----------------
__global__ __launch_bounds__(256) void kv_reduce(
    const float* __restrict__ part, const int* __restrict__ grange,
    float* __restrict__ KV, float* __restrict__ Ks)
{
    int blk = blockIdx.x;
    int c = blk % KCLS;
    int bh = blk / KCLS;
    int b = bh >> 3, h = bh & 7;
    int t = threadIdx.x;
    const float* pb = part + (size_t)bh * NGRP * 1056;
    int g0 = grange[(b * KCLS + c) * 2];
    int g1 = grange[(b * KCLS + c) * 2 + 1];
    float4 acc = {0, 0, 0, 0};
    float ka = 0.f;
    for (int gg = g0; gg < g1; ++gg) {
        float4 v = *(const float4*)(pb + (size_t)gg * 1056 + t * 4);
        acc.x += v.x; acc.y += v.y; acc.z += v.z; acc.w += v.w;
        if (t < 32) ka += pb[(size_t)gg * 1056 + 1024 + t];
    }
    *(float4*)(KV + ((size_t)(b * KCLS + c) * NHEAD + h) * HD * HD + t * 4) = acc;
    if (t < 32) Ks[((size_t)(b * KCLS + c) * NHEAD + h) * HD + t] = ka;
}

// ---------------- msg via MFMA ----------------
__global__ __launch_bounds__(256) void msg_kernel(
    const unsigned short* __restrict__ Qs, const float* __restrict__ KV,
    const float* __restrict__ Ks, const int* __restrict__ pidxp,
    const int* __restrict__ wseg, unsigned short* __restrict__ msgb)
{
    int b = blockIdx.x / NWIN, w = blockIdx.x % NWIN;
    int c = wseg[b * NWIN + w];
    if (c < 0) return;
    __shared__ unsigned short sQ[64 * DM];
    __shared__ unsigned short kvT[NHEAD * HD * HD];
    __shared__ float sKs[NHEAD * HD];
    __shared__ float zl[64 * NHEAD];
    __shared__ int sTok[64];
    int t = threadIdx.x;
    int wv = t >> 6, lane = t & 63;

    if (t < 64) sTok[t] = pidxp[b * PADPOS + w * 64 + t];
    { int h = t >> 5, d = t & 31;
      sKs[h * HD + d] = Ks[((size_t)(b * KCLS + c) * NHEAD + h) * HD + d]; }
    const float* kvsrc = KV + (size_t)(b * KCLS + c) * NHEAD * HD * HD;
    #pragma unroll
    for (int i = 0; i < 8; ++i) {
        int q = i * 256 + t;
        float4 v = ((const float4*)kvsrc)[q];
        int g = q * 4;
        int h = g >> 10, rem = g & 1023;
        int d = rem >> 5, e = rem & 31;
        kvT[h * 1024 + (e + 0) * 32 + d] = f2bf(v.x);
        kvT[h * 1024 + (e + 1) * 32 + d] = f2bf(v.y);
        kvT[h * 1024 + (e + 2) * 32 + d] = f2bf(v.z);
        kvT[h * 1024 + (e + 3) * 32 + d] = f2bf(v.w);
    }
    const unsigned short* qsrc = Qs + (size_t)(b * PADPOS + w * 64) * DM;
    #pragma unroll
    for (int i = 0; i < 8; ++i) {
        int q = i * 256 + t;
        *(bf16x8*)(sQ + q * 8) = *(const bf16x8*)(qsrc + q * 8);
    }
    __syncthreads();

    #pragma unroll
    for (int i = 0; i < 2; ++i) {
        int idx = i * 256 + t;
        int r = idx >> 3, h = idx & 7;
        float z = 0.f;
        #pragma unroll
        for (int d8 = 0; d8 < 4; ++d8) {
            bf16x8 qv = *(const bf16x8*)(sQ + r * DM + h * 32 + d8 * 8);
            #pragma unroll
            for (int j = 0; j < 8; ++j)
                z = fmaf(bf2f((unsigned short)qv[j]), sKs[h * HD + d8 * 8 + j], z);
        }
        zl[r * NHEAD + h] = z;
    }
    __syncthreads();

    int li = lane & 15, lg = lane >> 4;
    #pragma unroll
    for (int hh = 0; hh < 2; ++hh) {
        int h = wv * 2 + hh;
        f32x4 acc[4][2];
        #pragma unroll
        for (int m = 0; m < 4; ++m)
            #pragma unroll
            for (int n = 0; n < 2; ++n)
                acc[m][n] = (f32x4){0.f, 0.f, 0.f, 0.f};
        bf16x8 bfr[2];
        #pragma unroll
        for (int n = 0; n < 2; ++n)
            bfr[n] = *(const bf16x8*)(kvT + h * 1024 + (n * 16 + li) * 32 + lg * 8);
        #pragma unroll
        for (int m = 0; m < 4; ++m) {
            bf16x8 af = *(const bf16x8*)(sQ + (m * 16 + li) * DM + h * 32 + lg * 8);
            #pragma unroll
            for (int n = 0; n < 2; ++n)
                acc[m][n] = __builtin_amdgcn_mfma_f32_16x16x32_bf16(af, bfr[n], acc[m][n], 0, 0, 0);
        }
        #pragma unroll
        for (int m = 0; m < 4; ++m)
            #pragma unroll
            for (int n = 0; n < 2; ++n)
                #pragma unroll
                for (int j = 0; j < 4; ++j) {
                    int r = m * 16 + lg * 4 + j;
                    int tok = sTok[r];
                    if (tok >= 0) {
                        float o = acc[m][n][j] / (zl[r * NHEAD + h] + 1e-6f);
                        msgb[(size_t)(b * SEQ + tok) * DM + h * 32 + n * 16 + li] = f2bf(o);
                    }
                }
    }
}

extern "C" void kernel_launch(void* const* d_in, const int* in_sizes, int n_in,
                              void* d_out, int out_size, void* d_ws, size_t ws_size,
                              hipStream_t stream)
{
    const float* feat = (const float*)d_in[1];
    const float* fc   = (const float*)d_in[2];
    const float* Wq   = (const float*)d_in[3];
    const float* Wk   = (const float*)d_in[4];
    const float* Wv   = (const float*)d_in[5];
    const float* Wm   = (const float*)d_in[6];
    const float* W1   = (const float*)d_in[7];
    const float* W2   = (const float*)d_in[8];
    const float* g1   = (const float*)d_in[9];
    const float* b1   = (const float*)d_in[10];
    const float* g2   = (const float*)d_in[11];
    const float* b2   = (const float*)d_in[12];
    float* x = (float*)d_out;

    char* ws = (char*)d_ws;
    auto alloc = [&](size_t bytes) { char* p = ws; ws += (bytes + 255) & ~(size_t)255; return p; };
    int*   seg    = (int*)  alloc((size_t)M_TOK * 4);
    int*   cnt    = (int*)  alloc((size_t)BATCH * 16 * KCLS * 4);
    int*   cbase  = (int*)  alloc((size_t)BATCH * 16 * KCLS * 4);
    int*   pidxp  = (int*)  alloc((size_t)BATCH * PADPOS * 4);
    int*   psegp  = (int*)  alloc((size_t)BATCH * PADPOS * 4);
    int*   sortposG = (int*)alloc((size_t)M_TOK * 4);
    int*   wseg   = (int*)  alloc((size_t)BATCH * NWIN * 4);
    int*   grange = (int*)  alloc((size_t)BATCH * KCLS * 2 * 4);
    int*   prange = (int*)  alloc((size_t)BATCH * KCLS * 2 * 4);
    float* fcn    = (float*)alloc((size_t)BATCH * KCLS * 4);
    float* KV     = (float*)alloc((size_t)BATCH * KCLS * NHEAD * HD * HD * 4);
    float* Ks     = (float*)alloc((size_t)BATCH * KCLS * NHEAD * HD * 4);
    unsigned short* xm = (unsigned short*)alloc((size_t)M_TOK * 512 * 2);
    char* bufA = alloc((size_t)M_TOK * 512 * 2);   // hb / msgb / part overlay
    unsigned short* Qs   = (unsigned short*)alloc((size_t)BATCH * PADPOS * DM * 2);
    unsigned short* Ksrt = (unsigned short*)alloc((size_t)BATCH * PADPOS * DM * 2);
    unsigned short* Vsrt = (unsigned short*)alloc((size_t)BATCH * PADPOS * DM * 2);
    unsigned short* WqkvT = (unsigned short*)alloc((size_t)NL * 768 * 256 * 2);
    unsigned short* WmT   = (unsigned short*)alloc((size_t)NL * 256 * 256 * 2);
    unsigned short* W1T   = (unsigned short*)alloc((size_t)NL * 512 * 512 * 2);
    unsigned short* W2T   = (unsigned short*)alloc((size_t)NL * 256 * 512 * 2);

    unsigned short* hb   = (unsigned short*)bufA;
    unsigned short* msgb = (unsigned short*)bufA;
    float*          part = (float*)bufA;

    transpose_all<<<NL * 160, 256, 0, stream>>>(Wq, Wk, Wv, Wm, W1, W2,
                                                WqkvT, WmT, W1T, W2T);

    fcn_kernel<<<BATCH * KCLS, 64, 0, stream>>>(fc, fcn);
    route_kernel<<<8192, 256, 0, stream>>>(feat, fc, fcn, x, xm, seg);

    seg_count<<<BATCH * 16, 256, 0, stream>>>(seg, cnt);
    seg_scan<<<1, 256, 0, stream>>>(cnt, cbase, wseg, psegp, grange, prange, pidxp);
    seg_scatter<<<BATCH * 16, 256, 0, stream>>>(seg, cbase, pidxp, sortposG);
    zero_pads<<<BATCH * KCLS, 256, 0, stream>>>(prange, Ksrt, Vsrt);

    for (int li = 0; li < NL; ++li) {
        const unsigned short* wqkv = WqkvT + (size_t)li * 768 * 256;
        const unsigned short* wm   = WmT + (size_t)li * 65536;
        const unsigned short* w1   = W1T + (size_t)li * 262144;
        const unsigned short* w2   = W2T + (size_t)li * 131072;

        mfma_gemm<256, 512, 1><<<dim3(256, 3), 512, 0, stream>>>(xm, wqkv, sortposG, Qs, Ksrt, Vsrt);

        kv_kernel<<<BATCH * NHEAD * KVWIN, 256, 0, stream>>>(Ksrt, Vsrt, part);
        kv_reduce<<<BATCH * NHEAD * KCLS, 256, 0, stream>>>(part, grange, KV, Ks);

        msg_kernel<<<BATCH * NWIN, 256, 0, stream>>>(Qs, KV, Ks, pidxp, wseg, msgb);

        gemm_ln<256, 1><<<512, 256, 0, stream>>>(msgb, wm, g1 + li * DM, b1 + li * DM, nullptr, xm);

        mfma_gemm<512, 512, 2><<<dim3(256, 2), 512, 0, stream>>>(xm, w1, nullptr, hb, nullptr, nullptr);

        gemm_ln<512, 2><<<512, 256, 0, stream>>>(hb, w2, g2 + li * DM, b2 + li * DM, x, xm);
    }
}

// Round 23
// 646.000 us; speedup vs baseline: 1.1404x; 1.1404x over previous
//
#include <hip/hip_runtime.h>
#include <hip/hip_bf16.h>
#include <math.h>

#define DM 256
#define NHEAD 8
#define HD 32
#define NL 4
#define BATCH 8
#define SEQ 4096
#define KCLS 10
#define M_TOK (BATCH*SEQ)   // 32768

#define BKG 64

#define PADPOS 5120          // padded sorted positions per batch (each cluster 64-aligned)
#define NWIN (PADPOS/64)     // 80 msg windows per batch
#define KVWIN 20             // kv windows per batch (256 positions each)
#define NGRP (KVWIN*4)       // 80 groups of 64 per batch-head

using bf16x8 = __attribute__((ext_vector_type(8))) short;
using f32x4  = __attribute__((ext_vector_type(4))) float;

__device__ __forceinline__ unsigned short f2bf(float f) {
    __hip_bfloat16 b = __float2bfloat16(f);
    return __builtin_bit_cast(unsigned short, b);
}
__device__ __forceinline__ float bf2f(unsigned short u) {
    unsigned v = (unsigned)u << 16;
    return __builtin_bit_cast(float, v);
}

__device__ __forceinline__ float wave_reduce_sum(float v) {
    #pragma unroll
    for (int off = 32; off > 0; off >>= 1) v += __shfl_xor(v, off, 64);
    return v;
}

// ---------------- fc norms ----------------
__global__ __launch_bounds__(64) void fcn_kernel(const float* __restrict__ fc,
                                                 float* __restrict__ fcn) {
    int bk = blockIdx.x;
    int lane = threadIdx.x;
    float4 fv = *(const float4*)(fc + (size_t)bk * DM + lane * 4);
    float n = fv.x*fv.x + fv.y*fv.y + fv.z*fv.z + fv.w*fv.w;
    n = wave_reduce_sum(n);
    if (lane == 0) fcn[bk] = sqrtf(n);
}

// ---------------- fused init + routing (64 lanes/token, fully coalesced) ----------------
__global__ void route_kernel(const float* __restrict__ feat, const float* __restrict__ fc,
                             const float* __restrict__ fcn,
                             float* __restrict__ x, unsigned short* __restrict__ xm,
                             int* __restrict__ seg) {
    int wid = (int)((blockIdx.x * (size_t)blockDim.x + threadIdx.x) >> 6);
    int lane = threadIdx.x & 63;
    if (wid >= M_TOK) return;
    int b = wid / SEQ;
    float4 xv = *(const float4*)(feat + (size_t)wid * DM + lane * 4);
    *(float4*)(x + (size_t)wid * DM + lane * 4) = xv;
    ushort4 u; u.x = f2bf(xv.x); u.y = f2bf(xv.y); u.z = f2bf(xv.z); u.w = f2bf(xv.w);
    *(ushort4*)(xm + (size_t)wid * 512 + lane * 4) = u;
    float nb2 = xv.x*xv.x + xv.y*xv.y + xv.z*xv.z + xv.w*xv.w;
    nb2 = wave_reduce_sum(nb2);
    float nb = sqrtf(nb2);
    float best = -1e30f; int bestk = 0;
    for (int k = 0; k < KCLS; ++k) {
        float4 fv = *(const float4*)(fc + ((size_t)(b * KCLS + k)) * DM + lane * 4);
        float d = fv.x*xv.x + fv.y*xv.y + fv.z*xv.z + fv.w*xv.w;
        d = wave_reduce_sum(d);
        float sim = d / fmaxf(fcn[b * KCLS + k] * nb, 1e-8f);
        if (sim > best) { best = sim; bestk = k; }
    }
    if (lane == 0) seg[wid] = bestk;
}

// ---------------- deterministic cluster counting-sort ----------------
__global__ __launch_bounds__(256) void seg_count(const int* __restrict__ seg,
                                                 int* __restrict__ cnt) {
    __shared__ int wc[4][KCLS];
    int b = blockIdx.x >> 4, chunk = blockIdx.x & 15;
    int t = threadIdx.x, w = t >> 6, lane = t & 63;
    int c = seg[b * SEQ + chunk * 256 + t];
    #pragma unroll
    for (int cc = 0; cc < KCLS; ++cc) {
        unsigned long long m = __ballot(c == cc);
        if (lane == 0) wc[w][cc] = __popcll(m);
    }
    __syncthreads();
    if (t < KCLS)
        cnt[(b * 16 + chunk) * KCLS + t] = wc[0][t] + wc[1][t] + wc[2][t] + wc[3][t];
}

__global__ __launch_bounds__(256) void seg_scan(const int* __restrict__ cnt,
                                                int* __restrict__ chunkbase,
                                                int* __restrict__ wseg,
                                                int* __restrict__ psegp,
                                                int* __restrict__ grange,
                                                int* __restrict__ prange,
                                                int* __restrict__ pidxp) {
    __shared__ int sTot[BATCH][KCLS];
    __shared__ int sBase[BATCH][KCLS];
    int tid = threadIdx.x;
    if (tid < BATCH * KCLS) {
        int b = tid / KCLS, c = tid % KCLS;
        int run = 0;
        #pragma unroll
        for (int j = 0; j < 16; ++j) run += cnt[(b * 16 + j) * KCLS + c];
        sTot[b][c] = run;
    }
    __syncthreads();
    if (tid < BATCH) {
        int b = tid, pb = 0;
        for (int c = 0; c < KCLS; ++c) {
            sBase[b][c] = pb;
            int psz = (sTot[b][c] + 63) & ~63;
            grange[(b * KCLS + c) * 2]     = pb >> 6;
            grange[(b * KCLS + c) * 2 + 1] = (pb + psz) >> 6;
            prange[(b * KCLS + c) * 2]     = pb + sTot[b][c];   // pad start
            prange[(b * KCLS + c) * 2 + 1] = pb + psz;          // pad end
            int w0 = pb >> 6, w1 = (pb + psz) >> 6;
            for (int w = w0; w < w1; ++w) wseg[b * NWIN + w] = c;
            pb += psz;
        }
        for (int w = pb >> 6; w < NWIN; ++w) wseg[b * NWIN + w] = -1;
    }
    __syncthreads();
    for (int i = tid; i < BATCH * PADPOS; i += 256) {
        int b = i / PADPOS, pos = i % PADPOS;
        int c = KCLS - 1;
        #pragma unroll
        for (int cc = KCLS - 1; cc >= 1; --cc)
            if (pos < sBase[b][cc]) c = cc - 1;
        psegp[i] = c;
        pidxp[i] = -1;                       // pad marker; scatter overwrites real slots
    }
    if (tid < BATCH * KCLS) {
        int b = tid / KCLS, c = tid % KCLS;
        int pre = 0;
        #pragma unroll
        for (int j = 0; j < 16; ++j) {
            chunkbase[(b * 16 + j) * KCLS + c] = sBase[b][c] + pre;
            pre += cnt[(b * 16 + j) * KCLS + c];
        }
    }
}

// scatter: pidxp[b][pos] = token; sortposG[b*SEQ+l] = b*PADPOS+pos
__global__ __launch_bounds__(256) void seg_scatter(const int* __restrict__ seg,
                                                   const int* __restrict__ chunkbase,
                                                   int* __restrict__ pidxp,
                                                   int* __restrict__ sortposG) {
    __shared__ int wc[4][KCLS];
    int b = blockIdx.x >> 4, chunk = blockIdx.x & 15;
    int t = threadIdx.x, w = t >> 6, lane = t & 63;
    int l = chunk * 256 + t;
    int c = seg[b * SEQ + l];
    int rank_w = 0;
    #pragma unroll
    for (int cc = 0; cc < KCLS; ++cc) {
        unsigned long long m = __ballot(c == cc);
        if (lane == 0) wc[w][cc] = __popcll(m);
        if (cc == c) rank_w = __popcll(m & ((1ULL << lane) - 1ULL));
    }
    __syncthreads();
    int rank = rank_w;
    for (int wp = 0; wp < 4; ++wp)
        if (wp < w) rank += wc[wp][c];
    int pos = chunkbase[(b * 16 + chunk) * KCLS + c] + rank;
    pidxp[b * PADPOS + pos] = l;
    sortposG[b * SEQ + l] = b * PADPOS + pos;
}

// ---------------- zero pad rows of sorted K/V (prange-driven, 80 blocks) ----------------
__global__ __launch_bounds__(256) void zero_pads(const int* __restrict__ prange,
                                                 unsigned short* __restrict__ Kb,
                                                 unsigned short* __restrict__ Vb) {
    int bc = blockIdx.x;               // b*KCLS + c
    int b = bc / KCLS;
    int ps = prange[bc * 2], pe = prange[bc * 2 + 1];
    int nrows = pe - ps;
    int t = threadIdx.x;
    bf16x8 z = (bf16x8){0,0,0,0,0,0,0,0};
    for (int idx = t; idx < nrows * 32; idx += 256) {
        int r = idx >> 5, c8 = (idx & 31) * 8;
        size_t row = (size_t)b * PADPOS + ps + r;
        *(bf16x8*)(Kb + row * DM + c8) = z;
        *(bf16x8*)(Vb + row * DM + c8) = z;
    }
}

// ---------------- fused weight transpose+convert: ALL layers in ONE dispatch ----------------
__global__ __launch_bounds__(256) void transpose_all(
    const float* __restrict__ Wq, const float* __restrict__ Wk,
    const float* __restrict__ Wv, const float* __restrict__ Wm,
    const float* __restrict__ W1, const float* __restrict__ W2,
    unsigned short* __restrict__ WqkvT, unsigned short* __restrict__ WmT,
    unsigned short* __restrict__ W1T, unsigned short* __restrict__ W2T)
{
    __shared__ float s[64][65];
    int bid = blockIdx.x;
    int li = bid / 160, r = bid % 160;
    const float* src; unsigned short* dst; int K, N, kx, ny;
    if (r < 64) {
        int which = r >> 4, idx = r & 15;
        K = 256; N = 256; kx = idx & 3; ny = idx >> 2;
        if (which == 0)      { src = Wq + (size_t)li*65536; dst = WqkvT + (size_t)li*768*256; }
        else if (which == 1) { src = Wk + (size_t)li*65536; dst = WqkvT + (size_t)li*768*256 + 65536; }
        else if (which == 2) { src = Wv + (size_t)li*65536; dst = WqkvT + (size_t)li*768*256 + 131072; }
        else                 { src = Wm + (size_t)li*65536; dst = WmT + (size_t)li*65536; }
    } else if (r < 128) {
        int idx = r - 64;
        K = 512; N = 512; kx = idx & 7; ny = idx >> 3;
        src = W1 + (size_t)li*262144; dst = W1T + (size_t)li*262144;
    } else {
        int idx = r - 128;
        K = 512; N = 256; kx = idx & 7; ny = idx >> 3;
        src = W2 + (size_t)li*131072; dst = W2T + (size_t)li*131072;
    }
    int k0 = kx * 64, n0 = ny * 64;
    int t = threadIdx.x;
    int rr = t >> 4, c4 = (t & 15) * 4;
    #pragma unroll
    for (int i = 0; i < 4; ++i) {
        float4 v = *(const float4*)(src + (size_t)(k0 + rr + i*16) * N + n0 + c4);
        s[c4+0][rr+i*16] = v.x; s[c4+1][rr+i*16] = v.y;
        s[c4+2][rr+i*16] = v.z; s[c4+3][rr+i*16] = v.w;
    }
    __syncthreads();
    #pragma unroll
    for (int i = 0; i < 4; ++i) {
        int nr = rr + i*16;
        ushort4 u;
        u.x = f2bf(s[nr][c4+0]); u.y = f2bf(s[nr][c4+1]);
        u.z = f2bf(s[nr][c4+2]); u.w = f2bf(s[nr][c4+3]);
        *(ushort4*)(dst + (size_t)(n0 + nr) * K + k0 + c4) = u;
    }
}

// ---------------- bf16 MFMA GEMM (128x256, 8 waves) + T2 LDS XOR swizzle ----------------
template<int KD, int AS, int MODE>
__global__ __launch_bounds__(512, 4) void mfma_gemm(
    const unsigned short* __restrict__ A, const unsigned short* __restrict__ Bt,
    const int* __restrict__ sortpos,
    unsigned short* __restrict__ Ob0, unsigned short* __restrict__ Ob1,
    unsigned short* __restrict__ Ob2)
{
    __shared__ unsigned short As[128 * BKG];   // 16 KB
    __shared__ unsigned short Bs[256 * BKG];   // 32 KB
    __shared__ int sPos[128];
    int t = threadIdx.x;
    int lane = t & 63;
    int w = t >> 6;
    int wm = w & 1, wn = w >> 1;
    int li = lane & 15, lg = lane >> 4;
    int bm = blockIdx.x * 128;
    int bn = blockIdx.y * 256;

    if (MODE == 1 && t < 128) sPos[t] = sortpos[bm + t];

    f32x4 acc[4][4];
    #pragma unroll
    for (int m = 0; m < 4; ++m)
        #pragma unroll
        for (int n = 0; n < 4; ++n)
            acc[m][n] = (f32x4){0.f, 0.f, 0.f, 0.f};

    for (int k0 = 0; k0 < KD; k0 += BKG) {
        #pragma unroll
        for (int i = 0; i < 2; ++i) {
            int chunk = i * 512 + t;
            int row = chunk >> 3, cc = chunk & 7;
            int scc = cc ^ (row & 7);
            __builtin_amdgcn_global_load_lds(
                (const __attribute__((address_space(1))) void*)(A + (size_t)(bm + row) * AS + k0 + scc * 8),
                (__attribute__((address_space(3))) void*)((char*)As + chunk * 16), 16, 0, 0);
        }
        #pragma unroll
        for (int i = 0; i < 4; ++i) {
            int chunk = i * 512 + t;
            int row = chunk >> 3, cc = chunk & 7;
            int scc = cc ^ (row & 7);
            __builtin_amdgcn_global_load_lds(
                (const __attribute__((address_space(1))) void*)(Bt + (size_t)(bn + row) * KD + k0 + scc * 8),
                (__attribute__((address_space(3))) void*)((char*)Bs + chunk * 16), 16, 0, 0);
        }
        asm volatile("s_waitcnt vmcnt(0)");
        __syncthreads();
        #pragma unroll
        for (int kk = 0; kk < 2; ++kk) {
            int jc = kk * 4 + lg;
            bf16x8 af[4], bfr[4];
            #pragma unroll
            for (int m = 0; m < 4; ++m) {
                int R = wm*64 + m*16 + li;
                af[m] = *(const bf16x8*)((const char*)As + R * 128 + ((jc ^ (R & 7)) << 4));
            }
            #pragma unroll
            for (int n = 0; n < 4; ++n) {
                int R = wn*64 + n*16 + li;
                bfr[n] = *(const bf16x8*)((const char*)Bs + R * 128 + ((jc ^ (R & 7)) << 4));
            }
            #pragma unroll
            for (int m = 0; m < 4; ++m)
                #pragma unroll
                for (int n = 0; n < 4; ++n)
                    acc[m][n] = __builtin_amdgcn_mfma_f32_16x16x32_bf16(af[m], bfr[n], acc[m][n], 0, 0, 0);
        }
        __syncthreads();
    }

    int lrow0 = wm * 64 + (lane >> 4) * 4;
    int lcol = wn * 64 + (lane & 15);
    if (MODE == 1) {
        unsigned short* Obuf = (bn < 256) ? Ob0 : (bn < 512) ? Ob1 : Ob2;
        const bool act = (bn < 512);
        #pragma unroll
        for (int m = 0; m < 4; ++m)
            #pragma unroll
            for (int n = 0; n < 4; ++n)
                #pragma unroll
                for (int j = 0; j < 4; ++j) {
                    float v = acc[m][n][j];
                    if (act) v = (v > 0.f) ? v + 1.f : expf(v);
                    int drow = sPos[lrow0 + m*16 + j];
                    Obuf[(size_t)drow * 256 + lcol + n*16] = f2bf(v);
                }
    } else {
        #pragma unroll
        for (int m = 0; m < 4; ++m)
            #pragma unroll
            for (int n = 0; n < 4; ++n)
                #pragma unroll
                for (int j = 0; j < 4; ++j)
                    Ob0[(size_t)(bm + lrow0 + m*16 + j) * 512 + bn + lcol + n*16] =
                        f2bf(fmaxf(acc[m][n][j], 0.f));
    }
}

// ---------------- fused GEMM + LayerNorm (BM=64, BN=256, 256 thr) + T2 swizzle ----------------
template<int KD, int LNMODE>
__global__ __launch_bounds__(256) void gemm_ln(
    const unsigned short* __restrict__ A, const unsigned short* __restrict__ Bt,
    const float* __restrict__ g, const float* __restrict__ bb,
    float* __restrict__ x, unsigned short* __restrict__ xm)
{
    __shared__ unsigned short As[64 * BKG];
    __shared__ unsigned short Bs[256 * BKG];
    __shared__ float redS[4][64];
    __shared__ float redQ[4][64];
    int t = threadIdx.x;
    int lane = t & 63;
    int w = t >> 6;
    int li = lane & 15, lg = lane >> 4;
    int bm = blockIdx.x * 64;

    f32x4 acc[4][4];
    #pragma unroll
    for (int m = 0; m < 4; ++m)
        #pragma unroll
        for (int n = 0; n < 4; ++n)
            acc[m][n] = (f32x4){0.f, 0.f, 0.f, 0.f};

    for (int k0 = 0; k0 < KD; k0 += BKG) {
        #pragma unroll
        for (int i = 0; i < 2; ++i) {
            int chunk = i * 256 + t;
            int row = chunk >> 3, cc = chunk & 7;
            int scc = cc ^ (row & 7);
            __builtin_amdgcn_global_load_lds(
                (const __attribute__((address_space(1))) void*)(A + (size_t)(bm + row) * KD + k0 + scc * 8),
                (__attribute__((address_space(3))) void*)((char*)As + chunk * 16), 16, 0, 0);
        }
        #pragma unroll
        for (int i = 0; i < 8; ++i) {
            int chunk = i * 256 + t;
            int row = chunk >> 3, cc = chunk & 7;
            int scc = cc ^ (row & 7);
            __builtin_amdgcn_global_load_lds(
                (const __attribute__((address_space(1))) void*)(Bt + (size_t)row * KD + k0 + scc * 8),
                (__attribute__((address_space(3))) void*)((char*)Bs + chunk * 16), 16, 0, 0);
        }
        asm volatile("s_waitcnt vmcnt(0)");
        __syncthreads();
        #pragma unroll
        for (int kk = 0; kk < 2; ++kk) {
            int jc = kk * 4 + lg;
            bf16x8 af[4], bfr[4];
            #pragma unroll
            for (int m = 0; m < 4; ++m) {
                int R = m*16 + li;
                af[m] = *(const bf16x8*)((const char*)As + R * 128 + ((jc ^ (R & 7)) << 4));
            }
            #pragma unroll
            for (int n = 0; n < 4; ++n) {
                int R = w*64 + n*16 + li;
                bfr[n] = *(const bf16x8*)((const char*)Bs + R * 128 + ((jc ^ (R & 7)) << 4));
            }
            #pragma unroll
            for (int m = 0; m < 4; ++m)
                #pragma unroll
                for (int n = 0; n < 4; ++n)
                    acc[m][n] = __builtin_amdgcn_mfma_f32_16x16x32_bf16(af[m], bfr[n], acc[m][n], 0, 0, 0);
        }
        __syncthreads();
    }

    float vs[4][4], vq[4][4];
    #pragma unroll
    for (int m = 0; m < 4; ++m)
        #pragma unroll
        for (int j = 0; j < 4; ++j) {
            float s = 0.f, q = 0.f;
            #pragma unroll
            for (int n = 0; n < 4; ++n) {
                float v = acc[m][n][j];
                s += v; q += v * v;
            }
            #pragma unroll
            for (int msk = 1; msk < 16; msk <<= 1) {
                s += __shfl_xor(s, msk, 64);
                q += __shfl_xor(q, msk, 64);
            }
            vs[m][j] = s; vq[m][j] = q;
        }
    if (li == 0) {
        #pragma unroll
        for (int m = 0; m < 4; ++m)
            #pragma unroll
            for (int j = 0; j < 4; ++j) {
                redS[w][m*16 + lg*4 + j] = vs[m][j];
                redQ[w][m*16 + lg*4 + j] = vq[m][j];
            }
    }
    __syncthreads();

    float gv[4], bv[4];
    #pragma unroll
    for (int n = 0; n < 4; ++n) {
        int col = w*64 + n*16 + li;
        gv[n] = g[col]; bv[n] = bb[col];
    }
    #pragma unroll
    for (int m = 0; m < 4; ++m)
        #pragma unroll
        for (int j = 0; j < 4; ++j) {
            int r = m*16 + lg*4 + j;
            float S = redS[0][r] + redS[1][r] + redS[2][r] + redS[3][r];
            float Q = redQ[0][r] + redQ[1][r] + redQ[2][r] + redQ[3][r];
            float mu = S * (1.f / 256.f);
            float var = Q * (1.f / 256.f) - mu * mu;
            float rs = rsqrtf(var + 1e-5f);
            #pragma unroll
            for (int n = 0; n < 4; ++n) {
                int col = w*64 + n*16 + li;
                float o = gv[n] * (acc[m][n][j] - mu) * rs + bv[n];
                if (LNMODE == 1) {
                    xm[(size_t)(bm + r) * 512 + 256 + col] = f2bf(o);
                } else {
                    size_t idx = (size_t)(bm + r) * 256 + col;
                    float xv = x[idx] + o;
                    x[idx] = xv;
                    xm[(size_t)(bm + r) * 512 + col] = f2bf(xv);
                }
            }
        }
}

// ---------------- KV / Ksum: fp32 LDS staging, per-64-group unconditional flush ----------------
__global__ __launch_bounds__(256) void kv_kernel(
    const unsigned short* __restrict__ Ksrt, const unsigned short* __restrict__ Vsrt,
    float* __restrict__ part)
{
    __shared__ float sK[64 * 33];
    __shared__ float sV[64 * 33];
    int blk = blockIdx.x;
    int s = blk % KVWIN;
    int bh = blk / KVWIN;
    int b = bh >> 3, h = bh & 7;
    int t = threadIdx.x;
    int d = t >> 3, e0 = (t & 7) * 4;
    int srow = t >> 2, soff = (t & 3) * 8;
    const size_t rowbase = (size_t)(b * PADPOS + s * 256);
    float* pball = part + ((size_t)bh * NGRP + s * 4) * 1056;

    for (int g = 0; g < 4; ++g) {
        size_t gsrc = (rowbase + g * 64 + srow) * DM + h * HD + soff;
        bf16x8 k8 = *(const bf16x8*)(Ksrt + gsrc);
        bf16x8 v8 = *(const bf16x8*)(Vsrt + gsrc);
        float4 ka, kb, va, vb;
        ka.x = bf2f((unsigned short)k8[0]); ka.y = bf2f((unsigned short)k8[1]);
        ka.z = bf2f((unsigned short)k8[2]); ka.w = bf2f((unsigned short)k8[3]);
        kb.x = bf2f((unsigned short)k8[4]); kb.y = bf2f((unsigned short)k8[5]);
        kb.z = bf2f((unsigned short)k8[6]); kb.w = bf2f((unsigned short)k8[7]);
        va.x = bf2f((unsigned short)v8[0]); va.y = bf2f((unsigned short)v8[1]);
        va.z = bf2f((unsigned short)v8[2]); va.w = bf2f((unsigned short)v8[3]);
        vb.x = bf2f((unsigned short)v8[4]); vb.y = bf2f((unsigned short)v8[5]);
        vb.z = bf2f((unsigned short)v8[6]); vb.w = bf2f((unsigned short)v8[7]);
        *(float4*)(sK + srow * 33 + soff)     = ka;
        *(float4*)(sK + srow * 33 + soff + 4) = kb;
        *(float4*)(sV + srow * 33 + soff)     = va;
        *(float4*)(sV + srow * 33 + soff + 4) = vb;
        __syncthreads();

        float4 a = {0.f, 0.f, 0.f, 0.f};
        float ks = 0.f;
        #pragma unroll 8
        for (int l = 0; l < 64; ++l) {
            float kd = sK[l * 33 + d];
            float4 v4 = *(const float4*)(sV + l * 33 + e0);
            a.x = fmaf(kd, v4.x, a.x);
            a.y = fmaf(kd, v4.y, a.y);
            a.z = fmaf(kd, v4.z, a.z);
            a.w = fmaf(kd, v4.w, a.w);
            ks += kd;
        }
        float* pb = pball + g * 1056;
        *(float4*)(pb + d * 32 + e0) = a;
        if ((t & 7) == 0) pb[1024 + d] = ks;
        __syncthreads();
    }
}

// ---------------- reduce group partials -> KV, Ks ----------------
__global__ __launch_bounds__(256) void kv_reduce(
    const float* __restrict__ part, const int* __restrict__ grange,
    float* __restrict__ KV, float* __restrict__ Ks)
{
    int blk = blockIdx.x;
    int c = blk % KCLS;
    int bh = blk / KCLS;
    int b = bh >> 3, h = bh & 7;
    int t = threadIdx.x;
    const float* pb = part + (size_t)bh * NGRP * 1056;
    int g0 = grange[(b * KCLS + c) * 2];
    int g1 = grange[(b * KCLS + c) * 2 + 1];
    float4 acc = {0, 0, 0, 0};
    float ka = 0.f;
    for (int gg = g0; gg < g1; ++gg) {
        float4 v = *(const float4*)(pb + (size_t)gg * 1056 + t * 4);
        acc.x += v.x; acc.y += v.y; acc.z += v.z; acc.w += v.w;
        if (t < 32) ka += pb[(size_t)gg * 1056 + 1024 + t];
    }
    *(float4*)(KV + ((size_t)(b * KCLS + c) * NHEAD + h) * HD * HD + t * 4) = acc;
    if (t < 32) Ks[((size_t)(b * KCLS + c) * NHEAD + h) * HD + t] = ka;
}

// ---------------- msg via MFMA ----------------
__global__ __launch_bounds__(256) void msg_kernel(
    const unsigned short* __restrict__ Qs, const float* __restrict__ KV,
    const float* __restrict__ Ks, const int* __restrict__ pidxp,
    const int* __restrict__ wseg, unsigned short* __restrict__ msgb)
{
    int b = blockIdx.x / NWIN, w = blockIdx.x % NWIN;
    int c = wseg[b * NWIN + w];
    if (c < 0) return;
    __shared__ unsigned short sQ[64 * DM];
    __shared__ unsigned short kvT[NHEAD * HD * HD];
    __shared__ float sKs[NHEAD * HD];
    __shared__ float zl[64 * NHEAD];
    __shared__ int sTok[64];
    int t = threadIdx.x;
    int wv = t >> 6, lane = t & 63;

    if (t < 64) sTok[t] = pidxp[b * PADPOS + w * 64 + t];
    { int h = t >> 5, d = t & 31;
      sKs[h * HD + d] = Ks[((size_t)(b * KCLS + c) * NHEAD + h) * HD + d]; }
    const float* kvsrc = KV + (size_t)(b * KCLS + c) * NHEAD * HD * HD;
    #pragma unroll
    for (int i = 0; i < 8; ++i) {
        int q = i * 256 + t;
        float4 v = ((const float4*)kvsrc)[q];
        int g = q * 4;
        int h = g >> 10, rem = g & 1023;
        int d = rem >> 5, e = rem & 31;
        kvT[h * 1024 + (e + 0) * 32 + d] = f2bf(v.x);
        kvT[h * 1024 + (e + 1) * 32 + d] = f2bf(v.y);
        kvT[h * 1024 + (e + 2) * 32 + d] = f2bf(v.z);
        kvT[h * 1024 + (e + 3) * 32 + d] = f2bf(v.w);
    }
    const unsigned short* qsrc = Qs + (size_t)(b * PADPOS + w * 64) * DM;
    #pragma unroll
    for (int i = 0; i < 8; ++i) {
        int q = i * 256 + t;
        *(bf16x8*)(sQ + q * 8) = *(const bf16x8*)(qsrc + q * 8);
    }
    __syncthreads();

    #pragma unroll
    for (int i = 0; i < 2; ++i) {
        int idx = i * 256 + t;
        int r = idx >> 3, h = idx & 7;
        float z = 0.f;
        #pragma unroll
        for (int d8 = 0; d8 < 4; ++d8) {
            bf16x8 qv = *(const bf16x8*)(sQ + r * DM + h * 32 + d8 * 8);
            #pragma unroll
            for (int j = 0; j < 8; ++j)
                z = fmaf(bf2f((unsigned short)qv[j]), sKs[h * HD + d8 * 8 + j], z);
        }
        zl[r * NHEAD + h] = z;
    }
    __syncthreads();

    int li = lane & 15, lg = lane >> 4;
    #pragma unroll
    for (int hh = 0; hh < 2; ++hh) {
        int h = wv * 2 + hh;
        f32x4 acc[4][2];
        #pragma unroll
        for (int m = 0; m < 4; ++m)
            #pragma unroll
            for (int n = 0; n < 2; ++n)
                acc[m][n] = (f32x4){0.f, 0.f, 0.f, 0.f};
        bf16x8 bfr[2];
        #pragma unroll
        for (int n = 0; n < 2; ++n)
            bfr[n] = *(const bf16x8*)(kvT + h * 1024 + (n * 16 + li) * 32 + lg * 8);
        #pragma unroll
        for (int m = 0; m < 4; ++m) {
            bf16x8 af = *(const bf16x8*)(sQ + (m * 16 + li) * DM + h * 32 + lg * 8);
            #pragma unroll
            for (int n = 0; n < 2; ++n)
                acc[m][n] = __builtin_amdgcn_mfma_f32_16x16x32_bf16(af, bfr[n], acc[m][n], 0, 0, 0);
        }
        #pragma unroll
        for (int m = 0; m < 4; ++m)
            #pragma unroll
            for (int n = 0; n < 2; ++n)
                #pragma unroll
                for (int j = 0; j < 4; ++j) {
                    int r = m * 16 + lg * 4 + j;
                    int tok = sTok[r];
                    if (tok >= 0) {
                        float o = acc[m][n][j] / (zl[r * NHEAD + h] + 1e-6f);
                        msgb[(size_t)(b * SEQ + tok) * DM + h * 32 + n * 16 + li] = f2bf(o);
                    }
                }
    }
}

extern "C" void kernel_launch(void* const* d_in, const int* in_sizes, int n_in,
                              void* d_out, int out_size, void* d_ws, size_t ws_size,
                              hipStream_t stream)
{
    const float* feat = (const float*)d_in[1];
    const float* fc   = (const float*)d_in[2];
    const float* Wq   = (const float*)d_in[3];
    const float* Wk   = (const float*)d_in[4];
    const float* Wv   = (const float*)d_in[5];
    const float* Wm   = (const float*)d_in[6];
    const float* W1   = (const float*)d_in[7];
    const float* W2   = (const float*)d_in[8];
    const float* g1   = (const float*)d_in[9];
    const float* b1   = (const float*)d_in[10];
    const float* g2   = (const float*)d_in[11];
    const float* b2   = (const float*)d_in[12];
    float* x = (float*)d_out;

    char* ws = (char*)d_ws;
    auto alloc = [&](size_t bytes) { char* p = ws; ws += (bytes + 255) & ~(size_t)255; return p; };
    int*   seg    = (int*)  alloc((size_t)M_TOK * 4);
    int*   cnt    = (int*)  alloc((size_t)BATCH * 16 * KCLS * 4);
    int*   cbase  = (int*)  alloc((size_t)BATCH * 16 * KCLS * 4);
    int*   pidxp  = (int*)  alloc((size_t)BATCH * PADPOS * 4);
    int*   psegp  = (int*)  alloc((size_t)BATCH * PADPOS * 4);
    int*   sortposG = (int*)alloc((size_t)M_TOK * 4);
    int*   wseg   = (int*)  alloc((size_t)BATCH * NWIN * 4);
    int*   grange = (int*)  alloc((size_t)BATCH * KCLS * 2 * 4);
    int*   prange = (int*)  alloc((size_t)BATCH * KCLS * 2 * 4);
    float* fcn    = (float*)alloc((size_t)BATCH * KCLS * 4);
    float* KV     = (float*)alloc((size_t)BATCH * KCLS * NHEAD * HD * HD * 4);
    float* Ks     = (float*)alloc((size_t)BATCH * KCLS * NHEAD * HD * 4);
    unsigned short* xm = (unsigned short*)alloc((size_t)M_TOK * 512 * 2);
    char* bufA = alloc((size_t)M_TOK * 512 * 2);   // hb / msgb / part overlay
    unsigned short* Qs   = (unsigned short*)alloc((size_t)BATCH * PADPOS * DM * 2);
    unsigned short* Ksrt = (unsigned short*)alloc((size_t)BATCH * PADPOS * DM * 2);
    unsigned short* Vsrt = (unsigned short*)alloc((size_t)BATCH * PADPOS * DM * 2);
    unsigned short* WqkvT = (unsigned short*)alloc((size_t)NL * 768 * 256 * 2);
    unsigned short* WmT   = (unsigned short*)alloc((size_t)NL * 256 * 256 * 2);
    unsigned short* W1T   = (unsigned short*)alloc((size_t)NL * 512 * 512 * 2);
    unsigned short* W2T   = (unsigned short*)alloc((size_t)NL * 256 * 512 * 2);

    unsigned short* hb   = (unsigned short*)bufA;
    unsigned short* msgb = (unsigned short*)bufA;
    float*          part = (float*)bufA;

    transpose_all<<<NL * 160, 256, 0, stream>>>(Wq, Wk, Wv, Wm, W1, W2,
                                                WqkvT, WmT, W1T, W2T);

    fcn_kernel<<<BATCH * KCLS, 64, 0, stream>>>(fc, fcn);
    route_kernel<<<8192, 256, 0, stream>>>(feat, fc, fcn, x, xm, seg);

    seg_count<<<BATCH * 16, 256, 0, stream>>>(seg, cnt);
    seg_scan<<<1, 256, 0, stream>>>(cnt, cbase, wseg, psegp, grange, prange, pidxp);
    seg_scatter<<<BATCH * 16, 256, 0, stream>>>(seg, cbase, pidxp, sortposG);
    zero_pads<<<BATCH * KCLS, 256, 0, stream>>>(prange, Ksrt, Vsrt);

    for (int li = 0; li < NL; ++li) {
        const unsigned short* wqkv = WqkvT + (size_t)li * 768 * 256;
        const unsigned short* wm   = WmT + (size_t)li * 65536;
        const unsigned short* w1   = W1T + (size_t)li * 262144;
        const unsigned short* w2   = W2T + (size_t)li * 131072;

        mfma_gemm<256, 512, 1><<<dim3(256, 3), 512, 0, stream>>>(xm, wqkv, sortposG, Qs, Ksrt, Vsrt);

        kv_kernel<<<BATCH * NHEAD * KVWIN, 256, 0, stream>>>(Ksrt, Vsrt, part);
        kv_reduce<<<BATCH * NHEAD * KCLS, 256, 0, stream>>>(part, grange, KV, Ks);

        msg_kernel<<<BATCH * NWIN, 256, 0, stream>>>(Qs, KV, Ks, pidxp, wseg, msgb);

        gemm_ln<256, 1><<<512, 256, 0, stream>>>(msgb, wm, g1 + li * DM, b1 + li * DM, nullptr, xm);

        mfma_gemm<512, 512, 2><<<dim3(256, 2), 512, 0, stream>>>(xm, w1, nullptr, hb, nullptr, nullptr);

        gemm_ln<512, 2><<<512, 256, 0, stream>>>(hb, w2, g2 + li * DM, b2 + li * DM, x, xm);
    }
}